// Round 1
// baseline (953.712 us; speedup 1.0000x reference)
//
#include <hip/hip_runtime.h>

#define NB 8
#define NN 100000
#define NC 90
#define SCORE_THR 0.05f
#define IOU_THR 0.5f
#define MAX_DET 100
#define PRE_NMS_K 512
#define NEGV -1000000000.0f
#define T0 0.9925f
#define CAP 1024
#define NBC (NB * NC)

__device__ __forceinline__ unsigned ordf(float s) {
    unsigned u = __float_as_uint(s);
    return (u & 0x80000000u) ? ~u : (u | 0x80000000u);
}
__device__ __forceinline__ float deordf(unsigned o) {
    return (o & 0x80000000u) ? __uint_as_float(o ^ 0x80000000u) : __uint_as_float(~o);
}
__device__ __forceinline__ unsigned long long mkkey(float s, unsigned idx) {
    return ((unsigned long long)ordf(s) << 32) | (unsigned long long)(0xFFFFFFFFu - idx);
}

// ---------------- Pass 1: single coalesced scan of scores, collect s >= T0 ----------------
__global__ __launch_bounds__(256) void k_collect(const float* __restrict__ scores,
                                                 unsigned* __restrict__ cnt,
                                                 unsigned long long* __restrict__ buf) {
    unsigned base = blockIdx.x * 4096u;
    #pragma unroll
    for (int i = 0; i < 4; ++i) {
        unsigned f = base + (threadIdx.x + i * 256u) * 4u;
        if (f >= 72000000u) break;
        float4 v = *reinterpret_cast<const float4*>(scores + f);
        float ss[4] = {v.x, v.y, v.z, v.w};
        #pragma unroll
        for (int e = 0; e < 4; ++e) {
            float s = ss[e];
            if (s >= T0) {
                unsigned g = f + (unsigned)e;
                unsigned b = g / 9000000u;
                unsigned rem = g - b * 9000000u;
                unsigned n = rem / 90u;
                unsigned c = rem - n * 90u;
                unsigned bc = b * 90u + c;
                unsigned slot = atomicAdd(&cnt[bc], 1u);
                if (slot < CAP) buf[(size_t)bc * CAP + slot] = mkkey(s, n);
            }
        }
    }
}

// ---------------- Fixup (only if count outside [512, CAP]; never for this input) ----------------
__global__ __launch_bounds__(256) void k_fixup(const float* __restrict__ scores,
                                               unsigned* __restrict__ cnt,
                                               unsigned long long* __restrict__ buf) {
    int bc = blockIdx.x;
    unsigned count = cnt[bc];
    if (count >= 512u && count <= CAP) return;
    int b = bc / NC, c = bc - (bc / NC) * NC;
    __shared__ unsigned hist[1024];
    __shared__ float s_cut;
    for (int i = threadIdx.x; i < 1024; i += 256) hist[i] = 0u;
    __syncthreads();
    for (int n = threadIdx.x; n < NN; n += 256) {
        float s = scores[((size_t)b * NN + n) * NC + c];
        if (s >= SCORE_THR) {
            int bin = (int)(s * 1024.0f);
            bin = bin < 0 ? 0 : (bin > 1023 ? 1023 : bin);
            atomicAdd(&hist[bin], 1u);
        }
    }
    __syncthreads();
    if (threadIdx.x == 0) {
        unsigned total = 0;
        for (int i = 0; i < 1024; ++i) total += hist[i];
        unsigned target = total < 512u ? total : 512u;
        float cut = 3.0e38f;
        if (target > 0) {
            unsigned cum = 0; int t = 1023;
            for (; t >= 0; --t) { cum += hist[t]; if (cum >= target) break; }
            cut = (float)t / 1024.0f;
            if (cut < SCORE_THR) cut = SCORE_THR;
        }
        s_cut = cut;
        cnt[bc] = 0u;
    }
    __syncthreads();
    float cut = s_cut;
    for (int n = threadIdx.x; n < NN; n += 256) {
        float s = scores[((size_t)b * NN + n) * NC + c];
        if (s >= SCORE_THR && s >= cut) {
            unsigned slot = atomicAdd(&cnt[bc], 1u);
            if (slot < CAP) buf[(size_t)bc * CAP + slot] = mkkey(s, (unsigned)n);
        }
    }
}

// ---------------- Pass 2: per-(b,c) bitonic sort of <=1024 keys, emit top-512 + boxes ----------------
__global__ __launch_bounds__(256) void k_sort(const float* __restrict__ boxes,
                                              const unsigned* __restrict__ cnt,
                                              const unsigned long long* __restrict__ buf,
                                              float* __restrict__ cand_score,
                                              float4* __restrict__ cand_box) {
    int bc = blockIdx.x;
    __shared__ unsigned long long keys[CAP];
    unsigned K = cnt[bc]; if (K > CAP) K = CAP;
    for (unsigned i = threadIdx.x; i < CAP; i += 256)
        keys[i] = (i < K) ? buf[(size_t)bc * CAP + i] : 0ULL;
    __syncthreads();
    for (unsigned k = 2; k <= CAP; k <<= 1) {
        for (unsigned j = k >> 1; j; j >>= 1) {
            for (unsigned i = threadIdx.x; i < CAP; i += 256) {
                unsigned ixj = i ^ j;
                if (ixj > i) {
                    unsigned long long a = keys[i], bv = keys[ixj];
                    bool desc = ((i & k) == 0);
                    if (desc ? (a < bv) : (a > bv)) { keys[i] = bv; keys[ixj] = a; }
                }
            }
            __syncthreads();
        }
    }
    int b = bc / NC;
    for (int r = threadIdx.x; r < PRE_NMS_K; r += 256) {
        unsigned long long key = keys[r];
        float s; float4 bx;
        if (key == 0ULL) { s = NEGV; bx = make_float4(0.f, 0.f, 0.f, 0.f); }
        else {
            s = deordf((unsigned)(key >> 32));
            unsigned n = 0xFFFFFFFFu - (unsigned)(key & 0xFFFFFFFFu);
            bx = *reinterpret_cast<const float4*>(boxes + ((size_t)b * NN + n) * 4);
        }
        cand_score[bc * PRE_NMS_K + r] = s;
        cand_box[bc * PRE_NMS_K + r] = bx;
    }
}

// ---------------- NMS: one wave per (b,c), 100 argmax+suppress iterations ----------------
__global__ __launch_bounds__(64) void k_nms(const float* __restrict__ cand_score,
                                            const float4* __restrict__ cand_box,
                                            float* __restrict__ sel_score,
                                            float4* __restrict__ sel_box) {
    #pragma clang fp contract(off)
    int bc = blockIdx.x;
    int lane = threadIdx.x;
    __shared__ float4 box_lds[PRE_NMS_K];
    float s[8], y1[8], x1[8], y2[8], x2[8], area[8];
    #pragma unroll
    for (int k = 0; k < 8; ++k) {
        int r = lane + 64 * k;
        s[k] = cand_score[bc * PRE_NMS_K + r];
        float4 bx = cand_box[bc * PRE_NMS_K + r];
        box_lds[r] = bx;
        y1[k] = bx.x; x1[k] = bx.y; y2[k] = bx.z; x2[k] = bx.w;
        area[k] = (y2[k] - y1[k]) * (x2[k] - x1[k]);
    }
    __syncthreads();
    for (int it = 0; it < MAX_DET; ++it) {
        float bs = s[0]; int bp = lane;
        #pragma unroll
        for (int k = 1; k < 8; ++k) {
            if (s[k] > bs) { bs = s[k]; bp = lane + 64 * k; }
        }
        for (int off = 1; off < 64; off <<= 1) {
            float os = __shfl_xor(bs, off);
            int op = __shfl_xor(bp, off);
            if (os > bs || (os == bs && op < bp)) { bs = os; bp = op; }
        }
        float4 wb = box_lds[bp];
        if (lane == 0) {
            sel_score[bc * MAX_DET + it] = bs;
            sel_box[bc * MAX_DET + it] = wb;
        }
        float wy1 = wb.x, wx1 = wb.y, wy2 = wb.z, wx2 = wb.w;
        float warea = (wy2 - wy1) * (wx2 - wx1);
        #pragma unroll
        for (int k = 0; k < 8; ++k) {
            float yy1 = fmaxf(wy1, y1[k]);
            float xx1 = fmaxf(wx1, x1[k]);
            float yy2 = fminf(wy2, y2[k]);
            float xx2 = fminf(wx2, x2[k]);
            float ih = fmaxf(yy2 - yy1, 0.0f);
            float iw = fmaxf(xx2 - xx1, 0.0f);
            float inter = ih * iw;
            float denom = ((warea + area[k]) - inter) + 1e-8f;
            float iou = inter / denom;
            int r = lane + 64 * k;
            if (iou > IOU_THR || r == bp) s[k] = NEGV;
        }
    }
}

// ---------------- Final: per-batch merge of 90 descending lists, top-100 ----------------
__global__ __launch_bounds__(64) void k_merge(const float* __restrict__ sel_score,
                                              const float4* __restrict__ sel_box,
                                              float* __restrict__ out) {
    int b = blockIdx.x;
    int lane = threadIdx.x;
    const float* ss = sel_score + b * NC * MAX_DET;
    __shared__ unsigned long long win[MAX_DET];
    int c1 = lane;          // classes 0..63
    int c2 = 64 + lane;     // classes 64..89 (lane < 26)
    int r1 = 0, r2 = 0;
    auto mk = [&](int c, int r) {
        float s = ss[c * MAX_DET + r];
        return mkkey(s, (unsigned)(c * MAX_DET + r));
    };
    unsigned long long k1 = mk(c1, 0);
    unsigned long long k2 = (lane < 26) ? mk(c2, 0) : 0ULL;
    for (int it = 0; it < MAX_DET; ++it) {
        unsigned long long loc = k1 > k2 ? k1 : k2;
        unsigned long long w = loc;
        for (int off = 1; off < 64; off <<= 1) {
            unsigned long long o = __shfl_xor(w, off);
            if (o > w) w = o;
        }
        if (lane == 0) win[it] = w;
        if (k1 == w) { r1++; k1 = (r1 < MAX_DET) ? mk(c1, r1) : 0ULL; }
        else if (lane < 26 && k2 == w) { r2++; k2 = (r2 < MAX_DET) ? mk(c2, r2) : 0ULL; }
    }
    __syncthreads();
    int nv = 0;
    for (int t = lane; t < MAX_DET; t += 64) {
        unsigned long long w = win[t];
        unsigned flat = 0xFFFFFFFFu - (unsigned)(w & 0xFFFFFFFFu);
        float sdec = deordf((unsigned)(w >> 32));
        bool valid = (w != 0ULL) && (sdec >= SCORE_THR);
        float4 bx = make_float4(0.f, 0.f, 0.f, 0.f);
        float so = 0.0f; int cls = 0;
        if (valid) {
            bx = sel_box[b * NC * MAX_DET + flat];
            so = sdec;
            cls = (int)(flat / MAX_DET);
            nv++;
        }
        float* ob = out + (size_t)(b * MAX_DET + t) * 4;
        ob[0] = bx.x; ob[1] = bx.y; ob[2] = bx.z; ob[3] = bx.w;
        out[NB * MAX_DET * 4 + b * MAX_DET + t] = so;
        out[NB * MAX_DET * 5 + b * MAX_DET + t] = (float)cls;
    }
    for (int off = 1; off < 64; off <<= 1) nv += __shfl_xor(nv, off);
    if (lane == 0) out[NB * MAX_DET * 6 + b] = (float)nv;
}

extern "C" void kernel_launch(void* const* d_in, const int* in_sizes, int n_in,
                              void* d_out, int out_size, void* d_ws, size_t ws_size,
                              hipStream_t stream) {
    const float* boxes = (const float*)d_in[0];
    const float* scores = (const float*)d_in[1];
    float* out = (float*)d_out;

    char* ws = (char*)d_ws;
    size_t off = 0;
    auto alloc = [&](size_t bytes) -> void* {
        void* p = ws + off;
        off = (off + bytes + 255) & ~(size_t)255;
        return p;
    };
    unsigned* cnt = (unsigned*)alloc((size_t)NBC * 4);
    unsigned long long* buf = (unsigned long long*)alloc((size_t)NBC * CAP * 8);
    float* cand_score = (float*)alloc((size_t)NBC * PRE_NMS_K * 4);
    float4* cand_box = (float4*)alloc((size_t)NBC * PRE_NMS_K * 16);
    float* sel_score = (float*)alloc((size_t)NBC * MAX_DET * 4);
    float4* sel_box = (float4*)alloc((size_t)NBC * MAX_DET * 16);

    hipMemsetAsync(cnt, 0, (size_t)NBC * 4, stream);
    k_collect<<<17579, 256, 0, stream>>>(scores, cnt, buf);
    k_fixup<<<NBC, 256, 0, stream>>>(scores, cnt, buf);
    k_sort<<<NBC, 256, 0, stream>>>(boxes, cnt, buf, cand_score, cand_box);
    k_nms<<<NBC, 64, 0, stream>>>(cand_score, cand_box, sel_score, sel_box);
    k_merge<<<NB, 64, 0, stream>>>(sel_score, sel_box, out);
}

// Round 2
// 279.670 us; speedup vs baseline: 3.4101x; 3.4101x over previous
//
#include <hip/hip_runtime.h>

#define NB 8
#define NN 100000
#define NC 90
#define SCORE_THR 0.05f
#define IOU_THR 0.5f
#define MAX_DET 100
#define PRE_NMS_K 512
#define NEGV -1000000000.0f
#define T0 0.9925f
#define CAP 1024
#define NBC (NB * NC)
#define NPART 32
#define CAPP 64
#define CNT_STRIDE 16  // u32 words per counter slot (64B line padding)

__device__ __forceinline__ unsigned ordf(float s) {
    unsigned u = __float_as_uint(s);
    return (u & 0x80000000u) ? ~u : (u | 0x80000000u);
}
__device__ __forceinline__ float deordf(unsigned o) {
    return (o & 0x80000000u) ? __uint_as_float(o ^ 0x80000000u) : __uint_as_float(~o);
}
__device__ __forceinline__ unsigned long long mkkey(float s, unsigned idx) {
    return ((unsigned long long)ordf(s) << 32) | (unsigned long long)(0xFFFFFFFFu - idx);
}

// ---------------- Pass 1: coalesced scan of scores, collect s >= T0 into 32 partitions ----------------
__global__ __launch_bounds__(256) void k_collect(const float* __restrict__ scores,
                                                 unsigned* __restrict__ cnt,
                                                 unsigned long long* __restrict__ buf) {
    unsigned part = blockIdx.x & (NPART - 1u);
    unsigned base = blockIdx.x * 4096u;
    #pragma unroll
    for (int i = 0; i < 4; ++i) {
        unsigned f = base + (threadIdx.x + i * 256u) * 4u;
        if (f >= 72000000u) break;
        float4 v = *reinterpret_cast<const float4*>(scores + f);
        float ss[4] = {v.x, v.y, v.z, v.w};
        #pragma unroll
        for (int e = 0; e < 4; ++e) {
            float s = ss[e];
            if (s >= T0) {
                unsigned g = f + (unsigned)e;
                unsigned b = g / 9000000u;
                unsigned rem = g - b * 9000000u;
                unsigned n = rem / 90u;
                unsigned c = rem - n * 90u;
                unsigned bc = b * 90u + c;
                unsigned slot = atomicAdd(&cnt[((size_t)part * NBC + bc) * CNT_STRIDE], 1u);
                if (slot < CAPP) buf[((size_t)part * NBC + bc) * CAPP + slot] = mkkey(s, n);
            }
        }
    }
}

// ---------------- Fixup (only if counts pathological; never for this input) ----------------
__global__ __launch_bounds__(256) void k_fixup(const float* __restrict__ scores,
                                               unsigned* __restrict__ cnt,
                                               unsigned long long* __restrict__ buf) {
    int bc = blockIdx.x;
    __shared__ unsigned s_total;
    __shared__ unsigned s_over;
    if (threadIdx.x == 0) { s_total = 0u; s_over = 0u; }
    __syncthreads();
    if (threadIdx.x < NPART) {
        unsigned v = cnt[((size_t)threadIdx.x * NBC + bc) * CNT_STRIDE];
        atomicAdd(&s_total, v);
        if (v > CAPP) atomicOr(&s_over, 1u);
    }
    __syncthreads();
    unsigned total = s_total;
    if (total >= 512u && total <= CAP && s_over == 0u) return;

    int b = bc / NC, c = bc - (bc / NC) * NC;
    __shared__ unsigned hist[1024];
    __shared__ float s_cut;
    for (int i = threadIdx.x; i < 1024; i += 256) hist[i] = 0u;
    __syncthreads();
    for (int n = threadIdx.x; n < NN; n += 256) {
        float s = scores[((size_t)b * NN + n) * NC + c];
        if (s >= SCORE_THR) {
            int bin = (int)(s * 1024.0f);
            bin = bin < 0 ? 0 : (bin > 1023 ? 1023 : bin);
            atomicAdd(&hist[bin], 1u);
        }
    }
    __syncthreads();
    if (threadIdx.x == 0) {
        unsigned tot = 0;
        for (int i = 0; i < 1024; ++i) tot += hist[i];
        unsigned target = tot < 512u ? tot : 512u;
        float cut = 3.0e38f;
        if (target > 0) {
            unsigned cum = 0; int t = 1023;
            for (; t >= 0; --t) { cum += hist[t]; if (cum >= target) break; }
            cut = (float)t / 1024.0f;
            if (cut < SCORE_THR) cut = SCORE_THR;
        }
        s_cut = cut;
    }
    __syncthreads();
    if (threadIdx.x < NPART) cnt[((size_t)threadIdx.x * NBC + bc) * CNT_STRIDE] = 0u;
    __syncthreads();
    float cut = s_cut;
    for (int n = threadIdx.x; n < NN; n += 256) {
        float s = scores[((size_t)b * NN + n) * NC + c];
        if (s >= SCORE_THR && s >= cut) {
            unsigned p = (unsigned)n & (NPART - 1u);
            unsigned slot = atomicAdd(&cnt[((size_t)p * NBC + bc) * CNT_STRIDE], 1u);
            if (slot < CAPP) buf[((size_t)p * NBC + bc) * CAPP + slot] = mkkey(s, (unsigned)n);
        }
    }
}

// ---------------- Fused: gather 32 segments -> bitonic sort 1024 -> NMS (wave 0) ----------------
__global__ __launch_bounds__(256) void k_sortnms(const float* __restrict__ boxes,
                                                 const unsigned* __restrict__ cnt,
                                                 const unsigned long long* __restrict__ buf,
                                                 float* __restrict__ sel_score,
                                                 float4* __restrict__ sel_box) {
    #pragma clang fp contract(off)
    int bc = blockIdx.x;
    int tid = threadIdx.x;
    __shared__ unsigned long long keys[CAP];
    __shared__ unsigned segc[NPART];
    __shared__ unsigned sego[NPART + 1];
    __shared__ float4 box_lds[PRE_NMS_K];
    __shared__ float area_lds[PRE_NMS_K];

    if (tid < NPART) {
        unsigned v = cnt[((size_t)tid * NBC + bc) * CNT_STRIDE];
        segc[tid] = v > CAPP ? CAPP : v;
    }
    __syncthreads();
    if (tid == 0) {
        unsigned acc = 0;
        #pragma unroll
        for (int p = 0; p < NPART; ++p) { sego[p] = acc; acc += segc[p]; }
        sego[NPART] = acc;
    }
    __syncthreads();
    for (int p = 0; p < NPART; ++p) {
        unsigned kp = segc[p], o = sego[p];
        for (unsigned i = tid; i < kp; i += 256)
            keys[o + i] = buf[((size_t)p * NBC + bc) * CAPP + i];
    }
    unsigned K = sego[NPART]; if (K > CAP) K = CAP;
    for (unsigned i = K + tid; i < CAP; i += 256) keys[i] = 0ULL;
    __syncthreads();

    // bitonic sort, descending
    for (unsigned k = 2; k <= CAP; k <<= 1) {
        for (unsigned j = k >> 1; j; j >>= 1) {
            for (unsigned i = tid; i < CAP; i += 256) {
                unsigned ixj = i ^ j;
                if (ixj > i) {
                    unsigned long long a = keys[i], bv = keys[ixj];
                    bool desc = ((i & k) == 0);
                    if (desc ? (a < bv) : (a > bv)) { keys[i] = bv; keys[ixj] = a; }
                }
            }
            __syncthreads();
        }
    }

    // gather boxes + areas for top-512
    int b = bc / NC;
    for (int r = tid; r < PRE_NMS_K; r += 256) {
        unsigned long long key = keys[r];
        float4 bx = make_float4(0.f, 0.f, 0.f, 0.f);
        if (key != 0ULL) {
            unsigned n = 0xFFFFFFFFu - (unsigned)(key & 0xFFFFFFFFu);
            bx = *reinterpret_cast<const float4*>(boxes + ((size_t)b * NN + n) * 4);
        }
        box_lds[r] = bx;
        area_lds[r] = (bx.z - bx.x) * (bx.w - bx.y);
    }
    __syncthreads();

    // NMS on wave 0 only
    if (tid < 64) {
        int lane = tid;
        unsigned long long kk[8];
        float y1[8], x1[8], y2[8], x2[8], ar[8];
        #pragma unroll
        for (int k = 0; k < 8; ++k) {
            int r = lane + 64 * k;
            kk[k] = keys[r];
            float4 bx = box_lds[r];
            y1[k] = bx.x; x1[k] = bx.y; y2[k] = bx.z; x2[k] = bx.w;
            ar[k] = area_lds[r];
        }
        for (int it = 0; it < MAX_DET; ++it) {
            unsigned long long bk = kk[0]; int bp = lane;
            #pragma unroll
            for (int k = 1; k < 8; ++k) {
                if (kk[k] > bk) { bk = kk[k]; bp = lane + 64 * k; }
            }
            for (int off = 1; off < 64; off <<= 1) {
                unsigned long long ok = __shfl_xor(bk, off);
                int op = __shfl_xor(bp, off);
                if (ok > bk) { bk = ok; bp = op; }
            }
            if (bk == 0ULL) {
                if (lane == 0) {
                    sel_score[bc * MAX_DET + it] = NEGV;
                    sel_box[bc * MAX_DET + it] = make_float4(0.f, 0.f, 0.f, 0.f);
                }
                continue;
            }
            float4 wb = box_lds[bp];
            if (lane == 0) {
                sel_score[bc * MAX_DET + it] = deordf((unsigned)(bk >> 32));
                sel_box[bc * MAX_DET + it] = wb;
            }
            float wy1 = wb.x, wx1 = wb.y, wy2 = wb.z, wx2 = wb.w;
            float warea = (wy2 - wy1) * (wx2 - wx1);
            #pragma unroll
            for (int k = 0; k < 8; ++k) {
                float yy1 = fmaxf(wy1, y1[k]);
                float xx1 = fmaxf(wx1, x1[k]);
                float yy2 = fminf(wy2, y2[k]);
                float xx2 = fminf(wx2, x2[k]);
                float ih = fmaxf(yy2 - yy1, 0.0f);
                float iw = fmaxf(xx2 - xx1, 0.0f);
                float inter = ih * iw;
                float denom = ((warea + ar[k]) - inter) + 1e-8f;
                float iou = inter / denom;
                int r = lane + 64 * k;
                if (iou > IOU_THR || r == bp) kk[k] = 0ULL;
            }
        }
    }
}

// ---------------- Final: per-batch merge of 90 descending lists, top-100 ----------------
__global__ __launch_bounds__(64) void k_merge(const float* __restrict__ sel_score,
                                              const float4* __restrict__ sel_box,
                                              float* __restrict__ out) {
    int b = blockIdx.x;
    int lane = threadIdx.x;
    const float* ss = sel_score + b * NC * MAX_DET;
    __shared__ unsigned long long win[MAX_DET];
    int c1 = lane;
    int c2 = 64 + lane;
    int r1 = 0, r2 = 0;
    auto mk = [&](int c, int r) {
        float s = ss[c * MAX_DET + r];
        return mkkey(s, (unsigned)(c * MAX_DET + r));
    };
    unsigned long long k1 = mk(c1, 0);
    unsigned long long k2 = (lane < 26) ? mk(c2, 0) : 0ULL;
    for (int it = 0; it < MAX_DET; ++it) {
        unsigned long long w = k1 > k2 ? k1 : k2;
        for (int off = 1; off < 64; off <<= 1) {
            unsigned long long o = __shfl_xor(w, off);
            if (o > w) w = o;
        }
        if (lane == 0) win[it] = w;
        if (k1 == w) { r1++; k1 = (r1 < MAX_DET) ? mk(c1, r1) : 0ULL; }
        else if (lane < 26 && k2 == w) { r2++; k2 = (r2 < MAX_DET) ? mk(c2, r2) : 0ULL; }
    }
    __syncthreads();
    int nv = 0;
    for (int t = lane; t < MAX_DET; t += 64) {
        unsigned long long w = win[t];
        unsigned flat = 0xFFFFFFFFu - (unsigned)(w & 0xFFFFFFFFu);
        float sdec = deordf((unsigned)(w >> 32));
        bool valid = (w != 0ULL) && (sdec >= SCORE_THR);
        float4 bx = make_float4(0.f, 0.f, 0.f, 0.f);
        float so = 0.0f; int cls = 0;
        if (valid) {
            bx = sel_box[b * NC * MAX_DET + flat];
            so = sdec;
            cls = (int)(flat / MAX_DET);
            nv++;
        }
        float* ob = out + (size_t)(b * MAX_DET + t) * 4;
        ob[0] = bx.x; ob[1] = bx.y; ob[2] = bx.z; ob[3] = bx.w;
        out[NB * MAX_DET * 4 + b * MAX_DET + t] = so;
        out[NB * MAX_DET * 5 + b * MAX_DET + t] = (float)cls;
    }
    for (int off = 1; off < 64; off <<= 1) nv += __shfl_xor(nv, off);
    if (lane == 0) out[NB * MAX_DET * 6 + b] = (float)nv;
}

extern "C" void kernel_launch(void* const* d_in, const int* in_sizes, int n_in,
                              void* d_out, int out_size, void* d_ws, size_t ws_size,
                              hipStream_t stream) {
    const float* boxes = (const float*)d_in[0];
    const float* scores = (const float*)d_in[1];
    float* out = (float*)d_out;

    char* ws = (char*)d_ws;
    size_t off = 0;
    auto alloc = [&](size_t bytes) -> void* {
        void* p = ws + off;
        off = (off + bytes + 255) & ~(size_t)255;
        return p;
    };
    unsigned* cnt = (unsigned*)alloc((size_t)NPART * NBC * CNT_STRIDE * 4);
    unsigned long long* buf = (unsigned long long*)alloc((size_t)NPART * NBC * CAPP * 8);
    float* sel_score = (float*)alloc((size_t)NBC * MAX_DET * 4);
    float4* sel_box = (float4*)alloc((size_t)NBC * MAX_DET * 16);

    hipMemsetAsync(cnt, 0, (size_t)NPART * NBC * CNT_STRIDE * 4, stream);
    k_collect<<<17579, 256, 0, stream>>>(scores, cnt, buf);
    k_fixup<<<NBC, 256, 0, stream>>>(scores, cnt, buf);
    k_sortnms<<<NBC, 256, 0, stream>>>(boxes, cnt, buf, sel_score, sel_box);
    k_merge<<<NB, 64, 0, stream>>>(sel_score, sel_box, out);
}

// Round 3
// 279.468 us; speedup vs baseline: 3.4126x; 1.0007x over previous
//
#include <hip/hip_runtime.h>

#define NB 8
#define NN 100000
#define NC 90
#define SCORE_THR 0.05f
#define IOU_THR 0.5f
#define MAX_DET 100
#define PRE_NMS_K 512
#define NEGV -1000000000.0f
#define T0 0.9925f
#define CAP 1024
#define NBC (NB * NC)
#define NPART 32
#define CAPP 64
#define CNT_STRIDE 16  // u32 words per counter slot (64B line padding)
#define CNT_WORDS ((size_t)NPART * NBC * CNT_STRIDE)

__device__ __forceinline__ unsigned ordf(float s) {
    unsigned u = __float_as_uint(s);
    return (u & 0x80000000u) ? ~u : (u | 0x80000000u);
}
__device__ __forceinline__ float deordf(unsigned o) {
    return (o & 0x80000000u) ? __uint_as_float(o ^ 0x80000000u) : __uint_as_float(~o);
}
__device__ __forceinline__ unsigned long long mkkey(float s, unsigned idx) {
    return ((unsigned long long)ordf(s) << 32) | (unsigned long long)(0xFFFFFFFFu - idx);
}

// ---------------- Zero the padded counters (1.47 MB) at streaming rate ----------------
__global__ __launch_bounds__(256) void k_zero(uint4* __restrict__ cnt4) {
    unsigned i = blockIdx.x * 256u + threadIdx.x;
    if (i < CNT_WORDS / 4) cnt4[i] = make_uint4(0u, 0u, 0u, 0u);
}

// ---------------- Pass 1: coalesced scan of scores, collect s >= T0 into 32 partitions ----------------
__global__ __launch_bounds__(256) void k_collect(const float* __restrict__ scores,
                                                 unsigned* __restrict__ cnt,
                                                 unsigned long long* __restrict__ buf) {
    unsigned part = blockIdx.x & (NPART - 1u);
    unsigned base = blockIdx.x * 4096u;
    #pragma unroll
    for (int i = 0; i < 4; ++i) {
        unsigned f = base + (threadIdx.x + i * 256u) * 4u;
        if (f >= 72000000u) break;
        float4 v = *reinterpret_cast<const float4*>(scores + f);
        float ss[4] = {v.x, v.y, v.z, v.w};
        #pragma unroll
        for (int e = 0; e < 4; ++e) {
            float s = ss[e];
            if (s >= T0) {
                unsigned g = f + (unsigned)e;
                unsigned b = g / 9000000u;
                unsigned rem = g - b * 9000000u;
                unsigned n = rem / 90u;
                unsigned c = rem - n * 90u;
                unsigned bc = b * 90u + c;
                unsigned slot = atomicAdd(&cnt[((size_t)part * NBC + bc) * CNT_STRIDE], 1u);
                if (slot < CAPP) buf[((size_t)part * NBC + bc) * CAPP + slot] = mkkey(s, n);
            }
        }
    }
}

// ---------------- Fixup (only if counts pathological; never for this input) ----------------
__global__ __launch_bounds__(256) void k_fixup(const float* __restrict__ scores,
                                               unsigned* __restrict__ cnt,
                                               unsigned long long* __restrict__ buf) {
    int bc = blockIdx.x;
    __shared__ unsigned s_total;
    __shared__ unsigned s_over;
    if (threadIdx.x == 0) { s_total = 0u; s_over = 0u; }
    __syncthreads();
    if (threadIdx.x < NPART) {
        unsigned v = cnt[((size_t)threadIdx.x * NBC + bc) * CNT_STRIDE];
        atomicAdd(&s_total, v);
        if (v > CAPP) atomicOr(&s_over, 1u);
    }
    __syncthreads();
    unsigned total = s_total;
    if (total >= 512u && total <= CAP && s_over == 0u) return;

    int b = bc / NC, c = bc - (bc / NC) * NC;
    __shared__ unsigned hist[1024];
    __shared__ float s_cut;
    for (int i = threadIdx.x; i < 1024; i += 256) hist[i] = 0u;
    __syncthreads();
    for (int n = threadIdx.x; n < NN; n += 256) {
        float s = scores[((size_t)b * NN + n) * NC + c];
        if (s >= SCORE_THR) {
            int bin = (int)(s * 1024.0f);
            bin = bin < 0 ? 0 : (bin > 1023 ? 1023 : bin);
            atomicAdd(&hist[bin], 1u);
        }
    }
    __syncthreads();
    if (threadIdx.x == 0) {
        unsigned tot = 0;
        for (int i = 0; i < 1024; ++i) tot += hist[i];
        unsigned target = tot < 512u ? tot : 512u;
        float cut = 3.0e38f;
        if (target > 0) {
            unsigned cum = 0; int t = 1023;
            for (; t >= 0; --t) { cum += hist[t]; if (cum >= target) break; }
            cut = (float)t / 1024.0f;
            if (cut < SCORE_THR) cut = SCORE_THR;
        }
        s_cut = cut;
    }
    __syncthreads();
    if (threadIdx.x < NPART) cnt[((size_t)threadIdx.x * NBC + bc) * CNT_STRIDE] = 0u;
    __syncthreads();
    float cut = s_cut;
    for (int n = threadIdx.x; n < NN; n += 256) {
        float s = scores[((size_t)b * NN + n) * NC + c];
        if (s >= SCORE_THR && s >= cut) {
            unsigned p = (unsigned)n & (NPART - 1u);
            unsigned slot = atomicAdd(&cnt[((size_t)p * NBC + bc) * CNT_STRIDE], 1u);
            if (slot < CAPP) buf[((size_t)p * NBC + bc) * CAPP + slot] = mkkey(s, (unsigned)n);
        }
    }
}

// ---------------- Fused: gather 32 segments -> bitonic sort 1024 -> NMS (wave 0) ----------------
__global__ __launch_bounds__(256) void k_sortnms(const float* __restrict__ boxes,
                                                 const unsigned* __restrict__ cnt,
                                                 const unsigned long long* __restrict__ buf,
                                                 float* __restrict__ sel_score,
                                                 float4* __restrict__ sel_box) {
    #pragma clang fp contract(off)
    int bc = blockIdx.x;
    int tid = threadIdx.x;
    __shared__ unsigned long long keys[CAP];
    __shared__ unsigned segc[NPART];
    __shared__ unsigned sego[NPART + 1];
    __shared__ float4 box_lds[PRE_NMS_K];
    __shared__ float area_lds[PRE_NMS_K];

    if (tid < NPART) {
        unsigned v = cnt[((size_t)tid * NBC + bc) * CNT_STRIDE];
        segc[tid] = v > CAPP ? CAPP : v;
    }
    __syncthreads();
    if (tid == 0) {
        unsigned acc = 0;
        #pragma unroll
        for (int p = 0; p < NPART; ++p) { sego[p] = acc; acc += segc[p]; }
        sego[NPART] = acc;
    }
    __syncthreads();
    for (int p = 0; p < NPART; ++p) {
        unsigned kp = segc[p], o = sego[p];
        for (unsigned i = tid; i < kp; i += 256)
            keys[o + i] = buf[((size_t)p * NBC + bc) * CAPP + i];
    }
    unsigned K = sego[NPART]; if (K > CAP) K = CAP;
    for (unsigned i = K + tid; i < CAP; i += 256) keys[i] = 0ULL;
    __syncthreads();

    // bitonic sort, descending
    for (unsigned k = 2; k <= CAP; k <<= 1) {
        for (unsigned j = k >> 1; j; j >>= 1) {
            for (unsigned i = tid; i < CAP; i += 256) {
                unsigned ixj = i ^ j;
                if (ixj > i) {
                    unsigned long long a = keys[i], bv = keys[ixj];
                    bool desc = ((i & k) == 0);
                    if (desc ? (a < bv) : (a > bv)) { keys[i] = bv; keys[ixj] = a; }
                }
            }
            __syncthreads();
        }
    }

    // gather boxes + areas for top-512
    int b = bc / NC;
    for (int r = tid; r < PRE_NMS_K; r += 256) {
        unsigned long long key = keys[r];
        float4 bx = make_float4(0.f, 0.f, 0.f, 0.f);
        if (key != 0ULL) {
            unsigned n = 0xFFFFFFFFu - (unsigned)(key & 0xFFFFFFFFu);
            bx = *reinterpret_cast<const float4*>(boxes + ((size_t)b * NN + n) * 4);
        }
        box_lds[r] = bx;
        area_lds[r] = (bx.z - bx.x) * (bx.w - bx.y);
    }
    __syncthreads();

    // NMS on wave 0 only
    if (tid < 64) {
        int lane = tid;
        unsigned long long kk[8];
        float y1[8], x1[8], y2[8], x2[8], ar[8];
        #pragma unroll
        for (int k = 0; k < 8; ++k) {
            int r = lane + 64 * k;
            kk[k] = keys[r];
            float4 bx = box_lds[r];
            y1[k] = bx.x; x1[k] = bx.y; y2[k] = bx.z; x2[k] = bx.w;
            ar[k] = area_lds[r];
        }
        for (int it = 0; it < MAX_DET; ++it) {
            unsigned long long bk = kk[0]; int bp = lane;
            #pragma unroll
            for (int k = 1; k < 8; ++k) {
                if (kk[k] > bk) { bk = kk[k]; bp = lane + 64 * k; }
            }
            for (int off = 1; off < 64; off <<= 1) {
                unsigned long long ok = __shfl_xor(bk, off);
                int op = __shfl_xor(bp, off);
                if (ok > bk) { bk = ok; bp = op; }
            }
            if (bk == 0ULL) {
                if (lane == 0) {
                    sel_score[bc * MAX_DET + it] = NEGV;
                    sel_box[bc * MAX_DET + it] = make_float4(0.f, 0.f, 0.f, 0.f);
                }
                continue;
            }
            float4 wb = box_lds[bp];
            if (lane == 0) {
                sel_score[bc * MAX_DET + it] = deordf((unsigned)(bk >> 32));
                sel_box[bc * MAX_DET + it] = wb;
            }
            float wy1 = wb.x, wx1 = wb.y, wy2 = wb.z, wx2 = wb.w;
            float warea = (wy2 - wy1) * (wx2 - wx1);
            #pragma unroll
            for (int k = 0; k < 8; ++k) {
                float yy1 = fmaxf(wy1, y1[k]);
                float xx1 = fmaxf(wx1, x1[k]);
                float yy2 = fminf(wy2, y2[k]);
                float xx2 = fminf(wx2, x2[k]);
                float ih = fmaxf(yy2 - yy1, 0.0f);
                float iw = fmaxf(xx2 - xx1, 0.0f);
                float inter = ih * iw;
                float denom = ((warea + ar[k]) - inter) + 1e-8f;
                float iou = inter / denom;
                int r = lane + 64 * k;
                if (iou > IOU_THR || r == bp) kk[k] = 0ULL;
            }
        }
    }
}

// ---------------- Final: per-batch merge of 90 descending lists, top-100 ----------------
__global__ __launch_bounds__(64) void k_merge(const float* __restrict__ sel_score,
                                              const float4* __restrict__ sel_box,
                                              float* __restrict__ out) {
    int b = blockIdx.x;
    int lane = threadIdx.x;
    const float* ss = sel_score + b * NC * MAX_DET;
    __shared__ unsigned long long win[MAX_DET];
    int c1 = lane;
    int c2 = 64 + lane;
    int r1 = 0, r2 = 0;
    auto mk = [&](int c, int r) {
        float s = ss[c * MAX_DET + r];
        return mkkey(s, (unsigned)(c * MAX_DET + r));
    };
    unsigned long long k1 = mk(c1, 0);
    unsigned long long k2 = (lane < 26) ? mk(c2, 0) : 0ULL;
    for (int it = 0; it < MAX_DET; ++it) {
        unsigned long long w = k1 > k2 ? k1 : k2;
        for (int off = 1; off < 64; off <<= 1) {
            unsigned long long o = __shfl_xor(w, off);
            if (o > w) w = o;
        }
        if (lane == 0) win[it] = w;
        if (k1 == w) { r1++; k1 = (r1 < MAX_DET) ? mk(c1, r1) : 0ULL; }
        else if (lane < 26 && k2 == w) { r2++; k2 = (r2 < MAX_DET) ? mk(c2, r2) : 0ULL; }
    }
    __syncthreads();
    int nv = 0;
    for (int t = lane; t < MAX_DET; t += 64) {
        unsigned long long w = win[t];
        unsigned flat = 0xFFFFFFFFu - (unsigned)(w & 0xFFFFFFFFu);
        float sdec = deordf((unsigned)(w >> 32));
        bool valid = (w != 0ULL) && (sdec >= SCORE_THR);
        float4 bx = make_float4(0.f, 0.f, 0.f, 0.f);
        float so = 0.0f; int cls = 0;
        if (valid) {
            bx = sel_box[b * NC * MAX_DET + flat];
            so = sdec;
            cls = (int)(flat / MAX_DET);
            nv++;
        }
        float* ob = out + (size_t)(b * MAX_DET + t) * 4;
        ob[0] = bx.x; ob[1] = bx.y; ob[2] = bx.z; ob[3] = bx.w;
        out[NB * MAX_DET * 4 + b * MAX_DET + t] = so;
        out[NB * MAX_DET * 5 + b * MAX_DET + t] = (float)cls;
    }
    for (int off = 1; off < 64; off <<= 1) nv += __shfl_xor(nv, off);
    if (lane == 0) out[NB * MAX_DET * 6 + b] = (float)nv;
}

extern "C" void kernel_launch(void* const* d_in, const int* in_sizes, int n_in,
                              void* d_out, int out_size, void* d_ws, size_t ws_size,
                              hipStream_t stream) {
    const float* boxes = (const float*)d_in[0];
    const float* scores = (const float*)d_in[1];
    float* out = (float*)d_out;

    char* ws = (char*)d_ws;
    size_t off = 0;
    auto alloc = [&](size_t bytes) -> void* {
        void* p = ws + off;
        off = (off + bytes + 255) & ~(size_t)255;
        return p;
    };
    unsigned* cnt = (unsigned*)alloc(CNT_WORDS * 4);
    unsigned long long* buf = (unsigned long long*)alloc((size_t)NPART * NBC * CAPP * 8);
    float* sel_score = (float*)alloc((size_t)NBC * MAX_DET * 4);
    float4* sel_box = (float4*)alloc((size_t)NBC * MAX_DET * 16);

    k_zero<<<(int)(CNT_WORDS / 4 + 255) / 256, 256, 0, stream>>>((uint4*)cnt);
    k_collect<<<17579, 256, 0, stream>>>(scores, cnt, buf);
    k_fixup<<<NBC, 256, 0, stream>>>(scores, cnt, buf);
    k_sortnms<<<NBC, 256, 0, stream>>>(boxes, cnt, buf, sel_score, sel_box);
    k_merge<<<NB, 64, 0, stream>>>(sel_score, sel_box, out);
}

// Round 4
// 241.315 us; speedup vs baseline: 3.9521x; 1.1581x over previous
//
#include <hip/hip_runtime.h>

#define NB 8
#define NN 100000
#define NC 90
#define SCORE_THR 0.05f
#define IOU_THR 0.5f
#define MAX_DET 100
#define PRE_NMS_K 512
#define NEGV -1000000000.0f
#define T0 0.9925f
#define CAP 1024
#define NBC (NB * NC)
#define CNT_STRIDE 16   // u32 words per counter (64B line padding)
#define CHUNK 1024
#define NCHUNK 98       // ceil(100000/1024)
#define LCAP 32

__device__ __forceinline__ unsigned ordf(float s) {
    unsigned u = __float_as_uint(s);
    return (u & 0x80000000u) ? ~u : (u | 0x80000000u);
}
__device__ __forceinline__ float deordf(unsigned o) {
    return (o & 0x80000000u) ? __uint_as_float(o ^ 0x80000000u) : __uint_as_float(~o);
}
__device__ __forceinline__ unsigned long long mkkey(float s, unsigned idx) {
    return ((unsigned long long)ordf(s) << 32) | (unsigned long long)(0xFFFFFFFFu - idx);
}

// ---------------- zero counters + overflow flags ----------------
__global__ __launch_bounds__(256) void k_zero(uint4* __restrict__ cnt4, uint4* __restrict__ ovf4) {
    unsigned i = blockIdx.x * 256u + threadIdx.x;
    if (i < (NBC * CNT_STRIDE) / 4) cnt4[i] = make_uint4(0u, 0u, 0u, 0u);
    if (i < NBC / 4) ovf4[i] = make_uint4(0u, 0u, 0u, 0u);
}

// ---------------- Pass 1: streaming scan, per-class LDS staging, 1 atomic per (block,class) ----------------
__global__ __launch_bounds__(512) void k_collect(const float* __restrict__ scores,
                                                 unsigned* __restrict__ cnt,
                                                 unsigned* __restrict__ ovf,
                                                 unsigned long long* __restrict__ buf) {
    __shared__ unsigned long long lst[NC][LCAP + 1];
    __shared__ unsigned lcnt[NC];
    int b = blockIdx.x / NCHUNK;
    int chunk = blockIdx.x - b * NCHUNK;
    int n0 = chunk * CHUNK;
    int ncount = NN - n0; if (ncount > CHUNK) ncount = CHUNK;
    int nf4 = (ncount * NC) >> 2;            // ncount*90 always divisible by 4
    const float4* base4 = reinterpret_cast<const float4*>(scores + ((size_t)b * NN + n0) * NC);

    for (int i = threadIdx.x; i < NC; i += 512) lcnt[i] = 0u;
    __syncthreads();

    for (int i = threadIdx.x; i < nf4; i += 512) {
        float4 v = base4[i];
        float ss[4] = {v.x, v.y, v.z, v.w};
        #pragma unroll
        for (int e = 0; e < 4; ++e) {
            if (ss[e] >= T0) {
                int local = 4 * i + e;
                int c = local % NC;
                int n = n0 + local / NC;
                unsigned slot = atomicAdd(&lcnt[c], 1u);
                if (slot < LCAP) lst[c][slot] = mkkey(ss[e], (unsigned)n);
                else atomicOr(&ovf[b * NC + c], 1u);   // ~never
            }
        }
    }
    __syncthreads();

    if (threadIdx.x < NC) {
        int c = threadIdx.x;
        unsigned k = lcnt[c]; if (k > LCAP) k = LCAP;
        if (k) {
            int bc = b * NC + c;
            unsigned basep = atomicAdd(&cnt[(size_t)bc * CNT_STRIDE], k);
            if (basep + k > CAP) atomicOr(&ovf[bc], 1u);
            unsigned lim = (basep + k <= CAP) ? k : (basep < CAP ? CAP - basep : 0u);
            for (unsigned j = 0; j < lim; ++j)
                buf[(size_t)bc * CAP + basep + j] = lst[c][j];
        }
    }
}

// ---------------- Fixup (exact rebuild; never fires for this input) ----------------
__global__ __launch_bounds__(256) void k_fixup(const float* __restrict__ scores,
                                               unsigned* __restrict__ cnt,
                                               const unsigned* __restrict__ ovf,
                                               unsigned long long* __restrict__ buf) {
    int bc = blockIdx.x;
    unsigned total = cnt[(size_t)bc * CNT_STRIDE];
    if (total >= 512u && total <= CAP && ovf[bc] == 0u) return;

    int b = bc / NC, c = bc - (bc / NC) * NC;
    __shared__ unsigned hist[1024];
    __shared__ float s_cut;
    for (int i = threadIdx.x; i < 1024; i += 256) hist[i] = 0u;
    __syncthreads();
    for (int n = threadIdx.x; n < NN; n += 256) {
        float s = scores[((size_t)b * NN + n) * NC + c];
        if (s >= SCORE_THR) {
            int bin = (int)(s * 1024.0f);
            bin = bin < 0 ? 0 : (bin > 1023 ? 1023 : bin);
            atomicAdd(&hist[bin], 1u);
        }
    }
    __syncthreads();
    if (threadIdx.x == 0) {
        unsigned tot = 0;
        for (int i = 0; i < 1024; ++i) tot += hist[i];
        unsigned target = tot < 512u ? tot : 512u;
        float cut = 3.0e38f;
        if (target > 0) {
            unsigned cum = 0; int t = 1023;
            for (; t >= 0; --t) { cum += hist[t]; if (cum >= target) break; }
            cut = (float)t / 1024.0f;
            if (cut < SCORE_THR) cut = SCORE_THR;
        }
        s_cut = cut;
        cnt[(size_t)bc * CNT_STRIDE] = 0u;
    }
    __syncthreads();
    float cut = s_cut;
    for (int n = threadIdx.x; n < NN; n += 256) {
        float s = scores[((size_t)b * NN + n) * NC + c];
        if (s >= SCORE_THR && s >= cut) {
            unsigned slot = atomicAdd(&cnt[(size_t)bc * CNT_STRIDE], 1u);
            if (slot < CAP) buf[(size_t)bc * CAP + slot] = mkkey(s, (unsigned)n);
        }
    }
}

// ---------------- Fused: gather -> bitonic sort 1024 -> NMS (wave 0) ----------------
__global__ __launch_bounds__(256) void k_sortnms(const float* __restrict__ boxes,
                                                 const unsigned* __restrict__ cnt,
                                                 const unsigned long long* __restrict__ buf,
                                                 float* __restrict__ sel_score,
                                                 float4* __restrict__ sel_box) {
    #pragma clang fp contract(off)
    int bc = blockIdx.x;
    int tid = threadIdx.x;
    __shared__ unsigned long long keys[CAP];
    __shared__ float4 box_lds[PRE_NMS_K];
    __shared__ float area_lds[PRE_NMS_K];

    unsigned K = cnt[(size_t)bc * CNT_STRIDE]; if (K > CAP) K = CAP;
    for (unsigned i = tid; i < CAP; i += 256)
        keys[i] = (i < K) ? buf[(size_t)bc * CAP + i] : 0ULL;
    __syncthreads();

    // bitonic sort, descending
    for (unsigned k = 2; k <= CAP; k <<= 1) {
        for (unsigned j = k >> 1; j; j >>= 1) {
            for (unsigned i = tid; i < CAP; i += 256) {
                unsigned ixj = i ^ j;
                if (ixj > i) {
                    unsigned long long a = keys[i], bv = keys[ixj];
                    bool desc = ((i & k) == 0);
                    if (desc ? (a < bv) : (a > bv)) { keys[i] = bv; keys[ixj] = a; }
                }
            }
            __syncthreads();
        }
    }

    // gather boxes + areas for top-512
    int b = bc / NC;
    for (int r = tid; r < PRE_NMS_K; r += 256) {
        unsigned long long key = keys[r];
        float4 bx = make_float4(0.f, 0.f, 0.f, 0.f);
        if (key != 0ULL) {
            unsigned n = 0xFFFFFFFFu - (unsigned)(key & 0xFFFFFFFFu);
            bx = *reinterpret_cast<const float4*>(boxes + ((size_t)b * NN + n) * 4);
        }
        box_lds[r] = bx;
        area_lds[r] = (bx.z - bx.x) * (bx.w - bx.y);
    }
    __syncthreads();

    // NMS on wave 0 only
    if (tid < 64) {
        int lane = tid;
        unsigned long long kk[8];
        float y1[8], x1[8], y2[8], x2[8], ar[8];
        #pragma unroll
        for (int k = 0; k < 8; ++k) {
            int r = lane + 64 * k;
            kk[k] = keys[r];
            float4 bx = box_lds[r];
            y1[k] = bx.x; x1[k] = bx.y; y2[k] = bx.z; x2[k] = bx.w;
            ar[k] = area_lds[r];
        }
        for (int it = 0; it < MAX_DET; ++it) {
            unsigned long long bk = kk[0]; int bp = lane;
            #pragma unroll
            for (int k = 1; k < 8; ++k) {
                if (kk[k] > bk) { bk = kk[k]; bp = lane + 64 * k; }
            }
            for (int off = 1; off < 64; off <<= 1) {
                unsigned long long ok = __shfl_xor(bk, off);
                int op = __shfl_xor(bp, off);
                if (ok > bk) { bk = ok; bp = op; }
            }
            if (bk == 0ULL) {
                if (lane == 0) {
                    sel_score[bc * MAX_DET + it] = NEGV;
                    sel_box[bc * MAX_DET + it] = make_float4(0.f, 0.f, 0.f, 0.f);
                }
                continue;
            }
            float4 wb = box_lds[bp];
            if (lane == 0) {
                sel_score[bc * MAX_DET + it] = deordf((unsigned)(bk >> 32));
                sel_box[bc * MAX_DET + it] = wb;
            }
            float wy1 = wb.x, wx1 = wb.y, wy2 = wb.z, wx2 = wb.w;
            float warea = (wy2 - wy1) * (wx2 - wx1);
            #pragma unroll
            for (int k = 0; k < 8; ++k) {
                float yy1 = fmaxf(wy1, y1[k]);
                float xx1 = fmaxf(wx1, x1[k]);
                float yy2 = fminf(wy2, y2[k]);
                float xx2 = fminf(wx2, x2[k]);
                float ih = fmaxf(yy2 - yy1, 0.0f);
                float iw = fmaxf(xx2 - xx1, 0.0f);
                float inter = ih * iw;
                float denom = ((warea + ar[k]) - inter) + 1e-8f;
                float iou = inter / denom;
                int r = lane + 64 * k;
                if (iou > IOU_THR || r == bp) kk[k] = 0ULL;
            }
        }
    }
}

// ---------------- Final: per-batch merge of 90 descending lists, top-100 ----------------
__global__ __launch_bounds__(64) void k_merge(const float* __restrict__ sel_score,
                                              const float4* __restrict__ sel_box,
                                              float* __restrict__ out) {
    int b = blockIdx.x;
    int lane = threadIdx.x;
    const float* ss = sel_score + b * NC * MAX_DET;
    __shared__ unsigned long long win[MAX_DET];
    int c1 = lane;
    int c2 = 64 + lane;
    int r1 = 0, r2 = 0;
    auto mk = [&](int c, int r) {
        float s = ss[c * MAX_DET + r];
        return mkkey(s, (unsigned)(c * MAX_DET + r));
    };
    unsigned long long k1 = mk(c1, 0);
    unsigned long long k2 = (lane < 26) ? mk(c2, 0) : 0ULL;
    for (int it = 0; it < MAX_DET; ++it) {
        unsigned long long w = k1 > k2 ? k1 : k2;
        for (int off = 1; off < 64; off <<= 1) {
            unsigned long long o = __shfl_xor(w, off);
            if (o > w) w = o;
        }
        if (lane == 0) win[it] = w;
        if (k1 == w) { r1++; k1 = (r1 < MAX_DET) ? mk(c1, r1) : 0ULL; }
        else if (lane < 26 && k2 == w) { r2++; k2 = (r2 < MAX_DET) ? mk(c2, r2) : 0ULL; }
    }
    __syncthreads();
    int nv = 0;
    for (int t = lane; t < MAX_DET; t += 64) {
        unsigned long long w = win[t];
        unsigned flat = 0xFFFFFFFFu - (unsigned)(w & 0xFFFFFFFFu);
        float sdec = deordf((unsigned)(w >> 32));
        bool valid = (w != 0ULL) && (sdec >= SCORE_THR);
        float4 bx = make_float4(0.f, 0.f, 0.f, 0.f);
        float so = 0.0f; int cls = 0;
        if (valid) {
            bx = sel_box[b * NC * MAX_DET + flat];
            so = sdec;
            cls = (int)(flat / MAX_DET);
            nv++;
        }
        float* ob = out + (size_t)(b * MAX_DET + t) * 4;
        ob[0] = bx.x; ob[1] = bx.y; ob[2] = bx.z; ob[3] = bx.w;
        out[NB * MAX_DET * 4 + b * MAX_DET + t] = so;
        out[NB * MAX_DET * 5 + b * MAX_DET + t] = (float)cls;
    }
    for (int off = 1; off < 64; off <<= 1) nv += __shfl_xor(nv, off);
    if (lane == 0) out[NB * MAX_DET * 6 + b] = (float)nv;
}

extern "C" void kernel_launch(void* const* d_in, const int* in_sizes, int n_in,
                              void* d_out, int out_size, void* d_ws, size_t ws_size,
                              hipStream_t stream) {
    const float* boxes = (const float*)d_in[0];
    const float* scores = (const float*)d_in[1];
    float* out = (float*)d_out;

    char* ws = (char*)d_ws;
    size_t off = 0;
    auto alloc = [&](size_t bytes) -> void* {
        void* p = ws + off;
        off = (off + bytes + 255) & ~(size_t)255;
        return p;
    };
    unsigned* cnt = (unsigned*)alloc((size_t)NBC * CNT_STRIDE * 4);
    unsigned* ovf = (unsigned*)alloc((size_t)NBC * 4);
    unsigned long long* buf = (unsigned long long*)alloc((size_t)NBC * CAP * 8);
    float* sel_score = (float*)alloc((size_t)NBC * MAX_DET * 4);
    float4* sel_box = (float4*)alloc((size_t)NBC * MAX_DET * 16);

    k_zero<<<(NBC * CNT_STRIDE / 4 + 255) / 256, 256, 0, stream>>>((uint4*)cnt, (uint4*)ovf);
    k_collect<<<NB * NCHUNK, 512, 0, stream>>>(scores, cnt, ovf, buf);
    k_fixup<<<NBC, 256, 0, stream>>>(scores, cnt, ovf, buf);
    k_sortnms<<<NBC, 256, 0, stream>>>(boxes, cnt, buf, sel_score, sel_box);
    k_merge<<<NB, 64, 0, stream>>>(sel_score, sel_box, out);
}

// Round 5
// 182.183 us; speedup vs baseline: 5.2349x; 1.3246x over previous
//
#include <hip/hip_runtime.h>

#define NB 8
#define NN 100000
#define NC 90
#define SCORE_THR 0.05f
#define IOU_THR 0.5f
#define MAX_DET 100
#define PRE_NMS_K 512
#define NEGV -1000000000.0f
#define T0 0.9925f
#define CAP 1024
#define NBC (NB * NC)
#define CNT_STRIDE 16   // u32 words per counter (64B line padding)
#define CHUNK 1024
#define NCHUNK 98       // ceil(100000/1024)
#define LCAP 32
// Exact: RN(inter/denom) > 0.5f  <=>  (double)inter > (0.5+2^-26)*(double)denom
// (denom has 24-bit mantissa; (1+2^-25) has 26 bits; product <= 50 bits -> exact in f64)
#define IOU_CMP_C 0x1.0000008p-1

__device__ __forceinline__ unsigned ordf(float s) {
    unsigned u = __float_as_uint(s);
    return (u & 0x80000000u) ? ~u : (u | 0x80000000u);
}
__device__ __forceinline__ float deordf(unsigned o) {
    return (o & 0x80000000u) ? __uint_as_float(o ^ 0x80000000u) : __uint_as_float(~o);
}
__device__ __forceinline__ unsigned long long mkkey(float s, unsigned idx) {
    return ((unsigned long long)ordf(s) << 32) | (unsigned long long)(0xFFFFFFFFu - idx);
}

// ---------------- zero counters + overflow flags ----------------
__global__ __launch_bounds__(256) void k_zero(uint4* __restrict__ cnt4, uint4* __restrict__ ovf4) {
    unsigned i = blockIdx.x * 256u + threadIdx.x;
    if (i < (NBC * CNT_STRIDE) / 4) cnt4[i] = make_uint4(0u, 0u, 0u, 0u);
    if (i < NBC / 4) ovf4[i] = make_uint4(0u, 0u, 0u, 0u);
}

// ---------------- Pass 1: streaming scan, per-class LDS staging, 1 atomic per (block,class) ----------------
__global__ __launch_bounds__(512) void k_collect(const float* __restrict__ scores,
                                                 unsigned* __restrict__ cnt,
                                                 unsigned* __restrict__ ovf,
                                                 unsigned long long* __restrict__ buf) {
    __shared__ unsigned long long lst[NC][LCAP + 1];
    __shared__ unsigned lcnt[NC];
    int b = blockIdx.x / NCHUNK;
    int chunk = blockIdx.x - b * NCHUNK;
    int n0 = chunk * CHUNK;
    int ncount = NN - n0; if (ncount > CHUNK) ncount = CHUNK;
    int nf4 = (ncount * NC) >> 2;            // ncount*90 always divisible by 4
    const float4* base4 = reinterpret_cast<const float4*>(scores + ((size_t)b * NN + n0) * NC);

    for (int i = threadIdx.x; i < NC; i += 512) lcnt[i] = 0u;
    __syncthreads();

    for (int i = threadIdx.x; i < nf4; i += 512) {
        float4 v = base4[i];
        float ss[4] = {v.x, v.y, v.z, v.w};
        #pragma unroll
        for (int e = 0; e < 4; ++e) {
            if (ss[e] >= T0) {
                int local = 4 * i + e;
                int c = local % NC;
                int n = n0 + local / NC;
                unsigned slot = atomicAdd(&lcnt[c], 1u);
                if (slot < LCAP) lst[c][slot] = mkkey(ss[e], (unsigned)n);
                else atomicOr(&ovf[b * NC + c], 1u);   // ~never
            }
        }
    }
    __syncthreads();

    if (threadIdx.x < NC) {
        int c = threadIdx.x;
        unsigned k = lcnt[c]; if (k > LCAP) k = LCAP;
        if (k) {
            int bc = b * NC + c;
            unsigned basep = atomicAdd(&cnt[(size_t)bc * CNT_STRIDE], k);
            if (basep + k > CAP) atomicOr(&ovf[bc], 1u);
            unsigned lim = (basep + k <= CAP) ? k : (basep < CAP ? CAP - basep : 0u);
            for (unsigned j = 0; j < lim; ++j)
                buf[(size_t)bc * CAP + basep + j] = lst[c][j];
        }
    }
}

// ---------------- Fused: (rebuild-if-bad) -> bitonic sort 1024 -> pointer-walk NMS (wave 0) ----------------
__global__ __launch_bounds__(256) void k_sortnms(const float* __restrict__ scores,
                                                 const float* __restrict__ boxes,
                                                 const unsigned* __restrict__ cnt,
                                                 const unsigned* __restrict__ ovf,
                                                 const unsigned long long* __restrict__ buf,
                                                 float* __restrict__ sel_score,
                                                 float4* __restrict__ sel_box) {
    #pragma clang fp contract(off)
    int bc = blockIdx.x;
    int tid = threadIdx.x;
    __shared__ unsigned long long keys[CAP];
    __shared__ float4 box_lds[PRE_NMS_K];
    __shared__ float area_lds[PRE_NMS_K];
    __shared__ unsigned hist[1024];
    __shared__ unsigned s_lcnt;
    __shared__ float s_cut;

    unsigned K = cnt[(size_t)bc * CNT_STRIDE];
    bool bad = (ovf[bc] != 0u) || (K < (unsigned)PRE_NMS_K) || (K > CAP);

    if (bad) {
        // exact rebuild directly into LDS (never fires for this input)
        int b = bc / NC, c = bc - (bc / NC) * NC;
        for (int i = tid; i < 1024; i += 256) hist[i] = 0u;
        if (tid == 0) s_lcnt = 0u;
        __syncthreads();
        for (int n = tid; n < NN; n += 256) {
            float s = scores[((size_t)b * NN + n) * NC + c];
            if (s >= SCORE_THR) {
                int bin = (int)(s * 1024.0f);
                bin = bin < 0 ? 0 : (bin > 1023 ? 1023 : bin);
                atomicAdd(&hist[bin], 1u);
            }
        }
        __syncthreads();
        if (tid == 0) {
            unsigned tot = 0;
            for (int i = 0; i < 1024; ++i) tot += hist[i];
            unsigned target = tot < (unsigned)PRE_NMS_K ? tot : (unsigned)PRE_NMS_K;
            float cut = 3.0e38f;
            if (target > 0) {
                unsigned cum = 0; int t = 1023;
                for (; t >= 0; --t) { cum += hist[t]; if (cum >= target) break; }
                cut = (float)t / 1024.0f;
                if (cut < SCORE_THR) cut = SCORE_THR;
            }
            s_cut = cut;
        }
        __syncthreads();
        float cut = s_cut;
        for (int n = tid; n < NN; n += 256) {
            float s = scores[((size_t)b * NN + n) * NC + c];
            if (s >= SCORE_THR && s >= cut) {
                unsigned slot = atomicAdd(&s_lcnt, 1u);
                if (slot < CAP) keys[slot] = mkkey(s, (unsigned)n);
            }
        }
        __syncthreads();
        K = s_lcnt; if (K > CAP) K = CAP;
        for (unsigned i = K + tid; i < CAP; i += 256) keys[i] = 0ULL;
        __syncthreads();
    } else {
        // wave-local ownership (thread t writes t, t+256, ...): no barrier needed before
        // the in-wave (j<64) bitonic stages.
        for (unsigned i = tid; i < CAP; i += 256)
            keys[i] = (i < K) ? buf[(size_t)bc * CAP + i] : 0ULL;
    }

    // bitonic sort, descending. Barrier only when data crosses 64-element (wave-owned)
    // blocks: before any j>=64 stage and the first stage after one. j<64 stages are
    // wave-synchronous (wave64 lockstep, in-order LDS pipe).
    bool prev_big = false;
    for (unsigned k2 = 2; k2 <= CAP; k2 <<= 1) {
        for (unsigned j = k2 >> 1; j; j >>= 1) {
            bool big = (j >= 64);
            if (big || prev_big) __syncthreads();
            #pragma unroll
            for (unsigned ii = 0; ii < 4; ++ii) {
                unsigned i = tid + ii * 256u;
                unsigned ixj = i ^ j;
                if (ixj > i) {
                    unsigned long long a = keys[i], bv = keys[ixj];
                    bool desc = ((i & k2) == 0);
                    if (desc ? (a < bv) : (a > bv)) { keys[i] = bv; keys[ixj] = a; }
                }
            }
            prev_big = big;
        }
    }
    __syncthreads();

    // gather boxes + areas for the (sorted) top-512
    int b = bc / NC;
    for (int r = tid; r < PRE_NMS_K; r += 256) {
        unsigned long long key = keys[r];
        float4 bx = make_float4(0.f, 0.f, 0.f, 0.f);
        if (key != 0ULL) {
            unsigned n = 0xFFFFFFFFu - (unsigned)(key & 0xFFFFFFFFu);
            bx = *reinterpret_cast<const float4*>(boxes + ((size_t)b * NN + n) * 4);
        }
        box_lds[r] = bx;
        area_lds[r] = (bx.z - bx.x) * (bx.w - bx.y);
    }
    __syncthreads();

    // NMS on wave 0: sorted keys => winner = first alive index (pointer walk via ballot)
    if (tid < 64) {
        int lane = tid;
        float y1[8], x1[8], y2[8], x2[8], ar[8];
        unsigned alive = 0u;                 // 8 candidates per lane, contiguous: r = lane*8+k
        #pragma unroll
        for (int k = 0; k < 8; ++k) {
            int r = lane * 8 + k;
            float4 bx = box_lds[r];
            y1[k] = bx.x; x1[k] = bx.y; y2[k] = bx.z; x2[k] = bx.w;
            ar[k] = area_lds[r];
            if (keys[r] != 0ULL) alive |= (1u << k);
        }
        for (int it = 0; it < MAX_DET; ++it) {
            unsigned long long bal = __ballot(alive != 0u);
            if (bal == 0ULL) {
                if (lane == 0) {
                    sel_score[bc * MAX_DET + it] = NEGV;
                    sel_box[bc * MAX_DET + it] = make_float4(0.f, 0.f, 0.f, 0.f);
                }
                continue;
            }
            int lw = __ffsll((unsigned long long)bal) - 1;
            unsigned aw = __shfl(alive, lw);
            int bit = __ffs(aw) - 1;
            int widx = lw * 8 + bit;
            float4 wb = box_lds[widx];       // broadcast LDS read
            float warea = area_lds[widx];
            if (lane == 0) {
                unsigned long long wk = keys[widx];
                sel_score[bc * MAX_DET + it] = deordf((unsigned)(wk >> 32));
                sel_box[bc * MAX_DET + it] = wb;
            }
            unsigned sup = 0u;
            #pragma unroll
            for (int k = 0; k < 8; ++k) {
                float yy1 = fmaxf(wb.x, y1[k]);
                float xx1 = fmaxf(wb.y, x1[k]);
                float yy2 = fminf(wb.z, y2[k]);
                float xx2 = fminf(wb.w, x2[k]);
                float ih = fmaxf(yy2 - yy1, 0.0f);
                float iw = fmaxf(xx2 - xx1, 0.0f);
                float inter = ih * iw;
                float denom = ((warea + ar[k]) - inter) + 1e-8f;
                if ((double)inter > IOU_CMP_C * (double)denom) sup |= (1u << k);
            }
            alive &= ~sup;
            if (lane == lw) alive &= ~(1u << bit);   // reference: idxs == j always suppressed
        }
    }
}

// ---------------- Final: per-batch merge of 90 descending lists, top-100 ----------------
__global__ __launch_bounds__(64) void k_merge(const float* __restrict__ sel_score,
                                              const float4* __restrict__ sel_box,
                                              float* __restrict__ out) {
    int b = blockIdx.x;
    int lane = threadIdx.x;
    const float* ss = sel_score + b * NC * MAX_DET;
    __shared__ unsigned long long win[MAX_DET];
    int c1 = lane;
    int c2 = 64 + lane;
    int r1 = 0, r2 = 0;
    auto mk = [&](int c, int r) {
        float s = ss[c * MAX_DET + r];
        return mkkey(s, (unsigned)(c * MAX_DET + r));
    };
    unsigned long long k1 = mk(c1, 0);
    unsigned long long k2 = (lane < 26) ? mk(c2, 0) : 0ULL;
    for (int it = 0; it < MAX_DET; ++it) {
        unsigned long long w = k1 > k2 ? k1 : k2;
        for (int off = 1; off < 64; off <<= 1) {
            unsigned long long o = __shfl_xor(w, off);
            if (o > w) w = o;
        }
        if (lane == 0) win[it] = w;
        if (k1 == w) { r1++; k1 = (r1 < MAX_DET) ? mk(c1, r1) : 0ULL; }
        else if (lane < 26 && k2 == w) { r2++; k2 = (r2 < MAX_DET) ? mk(c2, r2) : 0ULL; }
    }
    __syncthreads();
    int nv = 0;
    for (int t = lane; t < MAX_DET; t += 64) {
        unsigned long long w = win[t];
        unsigned flat = 0xFFFFFFFFu - (unsigned)(w & 0xFFFFFFFFu);
        float sdec = deordf((unsigned)(w >> 32));
        bool valid = (w != 0ULL) && (sdec >= SCORE_THR);
        float4 bx = make_float4(0.f, 0.f, 0.f, 0.f);
        float so = 0.0f; int cls = 0;
        if (valid) {
            bx = sel_box[b * NC * MAX_DET + flat];
            so = sdec;
            cls = (int)(flat / MAX_DET);
            nv++;
        }
        float* ob = out + (size_t)(b * MAX_DET + t) * 4;
        ob[0] = bx.x; ob[1] = bx.y; ob[2] = bx.z; ob[3] = bx.w;
        out[NB * MAX_DET * 4 + b * MAX_DET + t] = so;
        out[NB * MAX_DET * 5 + b * MAX_DET + t] = (float)cls;
    }
    for (int off = 1; off < 64; off <<= 1) nv += __shfl_xor(nv, off);
    if (lane == 0) out[NB * MAX_DET * 6 + b] = (float)nv;
}

extern "C" void kernel_launch(void* const* d_in, const int* in_sizes, int n_in,
                              void* d_out, int out_size, void* d_ws, size_t ws_size,
                              hipStream_t stream) {
    const float* boxes = (const float*)d_in[0];
    const float* scores = (const float*)d_in[1];
    float* out = (float*)d_out;

    char* ws = (char*)d_ws;
    size_t off = 0;
    auto alloc = [&](size_t bytes) -> void* {
        void* p = ws + off;
        off = (off + bytes + 255) & ~(size_t)255;
        return p;
    };
    unsigned* cnt = (unsigned*)alloc((size_t)NBC * CNT_STRIDE * 4);
    unsigned* ovf = (unsigned*)alloc((size_t)NBC * 4);
    unsigned long long* buf = (unsigned long long*)alloc((size_t)NBC * CAP * 8);
    float* sel_score = (float*)alloc((size_t)NBC * MAX_DET * 4);
    float4* sel_box = (float4*)alloc((size_t)NBC * MAX_DET * 16);

    k_zero<<<(NBC * CNT_STRIDE / 4 + 255) / 256, 256, 0, stream>>>((uint4*)cnt, (uint4*)ovf);
    k_collect<<<NB * NCHUNK, 512, 0, stream>>>(scores, cnt, ovf, buf);
    k_sortnms<<<NBC, 256, 0, stream>>>(scores, boxes, cnt, ovf, buf, sel_score, sel_box);
    k_merge<<<NB, 64, 0, stream>>>(sel_score, sel_box, out);
}